// Round 5
// baseline (312.078 us; speedup 1.0000x reference)
//
#include <hip/hip_runtime.h>
#include <hip/hip_bf16.h>

// Problem: B=4, T=2048, DIM=1024, H=16, DH=64.  fp32 in/out, bf16 MFMA inside.
// qkv col o = d*48 + kk*16 + h (d outermost, h innermost).

typedef __attribute__((ext_vector_type(8))) short short8;
typedef __attribute__((ext_vector_type(4))) float floatx4;
typedef __attribute__((ext_vector_type(16))) float floatx16;

static __device__ __forceinline__ floatx4 mfma16(short8 a, short8 b, floatx4 c) {
    return __builtin_amdgcn_mfma_f32_16x16x32_bf16(a, b, c, 0, 0, 0);
}
static __device__ __forceinline__ floatx16 mfma32(short8 a, short8 b, floatx16 c) {
    return __builtin_amdgcn_mfma_f32_32x32x16_bf16(a, b, c, 0, 0, 0);
}

static __device__ __forceinline__ unsigned short f2bf_bits(float f) {
    __hip_bfloat16 h = __float2bfloat16(f);
    return *reinterpret_cast<unsigned short*>(&h);
}

static __device__ __forceinline__ float fast_exp2(float x) {
#if __has_builtin(__builtin_amdgcn_exp2f)
    return __builtin_amdgcn_exp2f(x);
#else
    return exp2f(x);
#endif
}

// pack two f32 -> one u32 of 2 bf16 (lo in [15:0], hi in [31:16])
static __device__ __forceinline__ unsigned cvt_pk_bf16(float lo, float hi) {
    unsigned r;
    asm("v_cvt_pk_bf16_f32 %0, %1, %2" : "=v"(r) : "v"(lo), "v"(hi));
    return r;
}

// m214-verified idiom: swap(pk(p0,p1), pk(p4,p5)) -> both outputs usable.
static __device__ __forceinline__ void plane32_swap(unsigned& x, unsigned& y) {
#if __has_builtin(__builtin_amdgcn_permlane32_swap)
    typedef unsigned int uintx2 __attribute__((ext_vector_type(2)));
    uintx2 r = __builtin_amdgcn_permlane32_swap(x, y, false, false);
    x = r[0];
    y = r[1];
#else
    asm volatile("v_permlane32_swap_b32 %0, %1" : "+v"(x), "+v"(y));
#endif
}

// async global->LDS, 16 B per lane; LDS dest = wave-uniform base + lane*16
#define GLD16(gptr, ldsptr)                                                  \
    __builtin_amdgcn_global_load_lds(                                        \
        (const __attribute__((address_space(1))) void*)(gptr),               \
        (__attribute__((address_space(3))) void*)(ldsptr), 16, 0, 0)

// ---------------------------------------------------------------------------
// Kernel 0: fp32 -> bf16 conversion
// ---------------------------------------------------------------------------
__global__ __launch_bounds__(256) void k_cvt(
    const float* __restrict__ src, unsigned short* __restrict__ dst, int n4)
{
    typedef __attribute__((ext_vector_type(4))) unsigned short ushort4v;
    for (int i = blockIdx.x * blockDim.x + threadIdx.x; i < n4;
         i += gridDim.x * blockDim.x) {
        const float4 v = ((const float4*)src)[i];
        ushort4v o;
        o.x = f2bf_bits(v.x);
        o.y = f2bf_bits(v.y);
        o.z = f2bf_bits(v.z);
        o.w = f2bf_bits(v.w);
        ((ushort4v*)dst)[i] = o;
    }
}

// ---------------------------------------------------------------------------
// Kernel 1: QKV projection (unchanged — verified).
// ---------------------------------------------------------------------------
__global__ __launch_bounds__(256) void k_qkv(
    const unsigned short* __restrict__ x,   // [8192][1024] bf16
    const unsigned short* __restrict__ wq,  // [3072][1024] bf16
    unsigned short* __restrict__ qb,        // [64 bh][2048 t][64 d]
    unsigned short* __restrict__ kb,        // [64 bh][2048 t][64 d]
    unsigned short* __restrict__ vb)        // [64 bh][64 d][2048 t]
{
    __shared__ unsigned short SM[16384];

    const int tid  = threadIdx.x;
    const int wave = tid >> 6, lane = tid & 63;
    const int quad = lane >> 4, l16 = lane & 15;
    const int wm = wave >> 1, wn = wave & 1;

    const int fid  = blockIdx.y * 24 + blockIdx.x;
    const int nfid = (fid & 7) * 192 + (fid >> 3);
    const int bx = nfid % 24;
    const int m0 = (nfid / 24) * 128;
    const int kk = bx >> 3;
    const int cb = bx & 7;

    const int srow = lane >> 2;          // 0..15
    const int sc8  = (lane & 3) * 8;     // 0,8,16,24
    const int row0 = wave * 32 + srow;
    const int row1 = row0 + 16;
    int bn0, bn1;
    if (kk < 2) {
        bn0 = (row0 & 63) * 48 + kk * 16 + cb * 2 + (row0 >> 6);
        bn1 = (row1 & 63) * 48 + kk * 16 + cb * 2 + (row1 >> 6);
    } else {
        bn0 = (cb * 8 + (row0 >> 4)) * 48 + 32 + (row0 & 15);
        bn1 = (cb * 8 + (row1 >> 4)) * 48 + 32 + (row1 & 15);
    }

    floatx4 acc[4][4];
#pragma unroll
    for (int i = 0; i < 4; i++)
#pragma unroll
        for (int j = 0; j < 4; j++) acc[i][j] = (floatx4){0.f, 0.f, 0.f, 0.f};

#define QKV_STAGE(BUF, K0)                                                        \
    do {                                                                          \
        GLD16(&x[(m0 + row0) * 1024 + (K0) + sc8],                                \
              &SM[(BUF) * 8192 + (wave * 32) * 32]);                              \
        GLD16(&x[(m0 + row1) * 1024 + (K0) + sc8],                                \
              &SM[(BUF) * 8192 + (wave * 32 + 16) * 32]);                         \
        GLD16(&wq[bn0 * 1024 + (K0) + sc8],                                       \
              &SM[(BUF) * 8192 + 4096 + (wave * 32) * 32]);                       \
        GLD16(&wq[bn1 * 1024 + (K0) + sc8],                                       \
              &SM[(BUF) * 8192 + 4096 + (wave * 32 + 16) * 32]);                  \
    } while (0)

    QKV_STAGE(0, 0);
    int buf = 0;
    for (int k0 = 0; k0 < 1024; k0 += 32) {
        __syncthreads();
        if (k0 + 32 < 1024) QKV_STAGE(buf ^ 1, k0 + 32);

        const unsigned short* Ab = &SM[buf * 8192];
        const unsigned short* Bb = &SM[buf * 8192 + 4096];
        short8 af[4], bfv[4];
#pragma unroll
        for (int mi = 0; mi < 4; mi++)
            af[mi] = *(const short8*)&Ab[(wm * 64 + mi * 16 + l16) * 32 + quad * 8];
#pragma unroll
        for (int ni = 0; ni < 4; ni++)
            bfv[ni] = *(const short8*)&Bb[(wn * 64 + ni * 16 + l16) * 32 + quad * 8];
#pragma unroll
        for (int mi = 0; mi < 4; mi++)
#pragma unroll
            for (int ni = 0; ni < 4; ni++)
                acc[mi][ni] = mfma16(af[mi], bfv[ni], acc[mi][ni]);
        buf ^= 1;
    }
    __syncthreads();

    if (kk == 2) {
#pragma unroll
        for (int ni = 0; ni < 4; ni++) {
            const int d = cb * 8 + wn * 4 + ni;
#pragma unroll
            for (int mi = 0; mi < 4; mi++) {
                const int m  = m0 + wm * 64 + mi * 16 + quad * 4;
                const int b  = m >> 11;
                const int tt = m & 2047;
                ushort4 pk;
                pk.x = f2bf_bits(acc[mi][ni][0]);
                pk.y = f2bf_bits(acc[mi][ni][1]);
                pk.z = f2bf_bits(acc[mi][ni][2]);
                pk.w = f2bf_bits(acc[mi][ni][3]);
                *(ushort4*)&vb[((b * 16 + l16) * 64 + d) * 2048 + tt] = pk;
            }
        }
    } else {
        const float scale = (kk == 0) ? 0.045084220027780106f : 1.0f;  // log2(e)/32
        unsigned short* dst = (kk == 0) ? qb : kb;
        const int b = m0 >> 11, tt0 = m0 & 2047;
#pragma unroll
        for (int s = 0; s < 2; s++) {
            if (wn == s) {
#pragma unroll
                for (int ni = 0; ni < 4; ni++) {
                    const int d = ni * 16 + l16;
#pragma unroll
                    for (int mi = 0; mi < 4; mi++) {
                        const int tl = wm * 64 + mi * 16 + quad * 4;
#pragma unroll
                        for (int r = 0; r < 4; r++)
                            SM[(tl + r) * 72 + d] = f2bf_bits(acc[mi][ni][r] * scale);
                    }
                }
            }
            __syncthreads();
#pragma unroll
            for (int u = 0; u < 4; u++) {
                const int w  = tid + u * 256;
                const int tl = w >> 3;
                const int ch = (w & 7) * 8;
                *(uint4*)&dst[((b * 16 + cb * 2 + s) * 2048 + tt0 + tl) * 64 + ch] =
                    *(const uint4*)&SM[tl * 72 + ch];
            }
            __syncthreads();
        }
    }
#undef QKV_STAGE
}

// ---------------------------------------------------------------------------
// Kernel 2: flash attention.  NEW this round: NO LDS STAGING AT ALL.
// K/V per head (256 KB each) is L2-resident (FETCH counter confirms re-reads
// never hit HBM), so the LDS tiles + barriers + vmcnt(0) drains were pure
// overhead (Common-mistake #7 / m169).  K and V fragments are read directly
// from global — layouts [bh][t][d] / [bh][d][t] match the fragment shapes
// exactly, so the arithmetic is bit-identical to round 3.  Zero barriers:
// waves free-run, compiler pipelines the pure global loads across the key
// loop.  Geometry = round 3 (512 blocks x 4 waves x 64 qrows/wave): keeps
// total L2 fragment traffic at ~1 GB (~17 TB/s < 34.5 ceiling); the 4 waves
// of a block walk the same K-tile near-lockstep so L1 absorbs the re-reads.
// ---------------------------------------------------------------------------
__global__ __launch_bounds__(256, 2) void k_attn(
    const unsigned short* __restrict__ qt,  // [64][2048][64]  (bh, t, d)
    const unsigned short* __restrict__ kt,  // [64][2048][64]
    const unsigned short* __restrict__ vg,  // [64][64][2048]  (bh, d, t)
    __hip_bfloat16* __restrict__ og)        // [4][2048][1024]
{
    const int tid  = threadIdx.x;
    const int wave = tid >> 6, lane = tid & 63;
    const int l31  = lane & 31, hi = lane >> 5;
    const int blk = blockIdx.x;
    const int bh  = (blk & 7) | ((blk >> 6) << 3);  // XCD-affine
    const int q0  = ((blk >> 3) & 7) * 256;
    const int qr  = q0 + wave * 64;

    // Q fragments (B operand [16 dk][32 qrow]: col=l31=qrow, k=hi*8+j)
    short8 qf[2][4];
#pragma unroll
    for (int qb2 = 0; qb2 < 2; qb2++)
#pragma unroll
        for (int ks = 0; ks < 4; ks++)
            qf[qb2][ks] = *(const short8*)
                &qt[(bh * 2048 + qr + qb2 * 32 + l31) * 64 + ks * 16 + hi * 8];

    float lsum[2] = {0.f, 0.f};
    floatx16 o[2][2];
#pragma unroll
    for (int qb2 = 0; qb2 < 2; qb2++)
#pragma unroll
        for (int db = 0; db < 2; db++)
#pragma unroll
            for (int r = 0; r < 16; r++) o[qb2][db][r] = 0.f;

    const unsigned short* kbase = &kt[bh * 2048 * 64];
    const unsigned short* vbase = &vg[bh * 64 * 2048];

#pragma unroll 2
    for (int j = 0; j < 2048; j += 32) {   // 32-key blocks
        // K fragments (A operand [32 key][16 dk]: row=l31, k=hi*8+j) — global
        short8 kf[4];
#pragma unroll
        for (int ks = 0; ks < 4; ks++)
            kf[ks] = *(const short8*)&kbase[(j + l31) * 64 + ks * 16 + hi * 8];

        // S^T = K Q^T
        floatx16 st[2];
#pragma unroll
        for (int qb2 = 0; qb2 < 2; qb2++)
#pragma unroll
            for (int r = 0; r < 16; r++) st[qb2][r] = 0.f;
        __builtin_amdgcn_s_setprio(1);
#pragma unroll
        for (int ks = 0; ks < 4; ks++)
#pragma unroll
            for (int qb2 = 0; qb2 < 2; qb2++)
                st[qb2] = mfma32(kf[ks], qf[qb2][ks], st[qb2]);
        __builtin_amdgcn_s_setprio(0);

        // V fragments (B operand [16 key][32 d]: col=l31=d, k=hi*8+jj) — global
        short8 vf[2][2];
#pragma unroll
        for (int db = 0; db < 2; db++)
#pragma unroll
            for (int hf = 0; hf < 2; hf++)
                vf[db][hf] = *(const short8*)
                    &vbase[(db * 32 + l31) * 2048 + j + hf * 16 + hi * 8];

        // softmax in-register; build PV A-frags via cvt_pk + permlane32
        short8 paf[2][2];
#pragma unroll
        for (int qb2 = 0; qb2 < 2; qb2++) {
            float p[16];
#pragma unroll
            for (int r = 0; r < 16; r++) p[r] = fast_exp2(st[qb2][r]);
            lsum[qb2] += (((p[0] + p[1]) + (p[2] + p[3])) +
                          ((p[4] + p[5]) + (p[6] + p[7]))) +
                         (((p[8] + p[9]) + (p[10] + p[11])) +
                          ((p[12] + p[13]) + (p[14] + p[15])));
#pragma unroll
            for (int hf = 0; hf < 2; hf++) {
                const int r0 = hf * 8;
                unsigned c01 = cvt_pk_bf16(p[r0 + 0], p[r0 + 1]);
                unsigned c23 = cvt_pk_bf16(p[r0 + 2], p[r0 + 3]);
                unsigned c45 = cvt_pk_bf16(p[r0 + 4], p[r0 + 5]);
                unsigned c67 = cvt_pk_bf16(p[r0 + 6], p[r0 + 7]);
                plane32_swap(c01, c45);  // -> a0 (keys hi*8+0,1), a2 (+4,5)
                plane32_swap(c23, c67);  // -> a1 (keys hi*8+2,3), a3 (+6,7)
                uint4 t4 = {c01, c23, c45, c67};
                paf[qb2][hf] = *reinterpret_cast<short8*>(&t4);
            }
        }

        // O += P V
        __builtin_amdgcn_s_setprio(1);
#pragma unroll
        for (int qb2 = 0; qb2 < 2; qb2++)
#pragma unroll
            for (int db = 0; db < 2; db++)
#pragma unroll
                for (int hf = 0; hf < 2; hf++)
                    o[qb2][db] = mfma32(paf[qb2][hf], vf[db][hf], o[qb2][db]);
        __builtin_amdgcn_s_setprio(0);
    }

    // each lane summed its hi-half keys; partner lane holds the complement
    lsum[0] += __shfl_xor(lsum[0], 32);
    lsum[1] += __shfl_xor(lsum[1], 32);

    // epilogue: o / l -> [b][t][h*64+d];  D layout: col=l31=d,
    // row(qrow) = (r&3) + 8*(r>>2) + 4*hi
    const int b = bh >> 4, h = bh & 15;
#pragma unroll
    for (int qb2 = 0; qb2 < 2; qb2++) {
#pragma unroll
        for (int r = 0; r < 16; r++) {
            const int qrl = (r & 3) + 8 * (r >> 2) + 4 * hi;
            const float inv = 1.0f / __shfl(lsum[qb2], qrl);
            const int t = qr + qb2 * 32 + qrl;
#pragma unroll
            for (int db = 0; db < 2; db++)
                og[(b * 2048 + t) * 1024 + h * 64 + db * 32 + l31] =
                    __float2bfloat16(o[qb2][db][r] * inv);
        }
    }
}

// ---------------------------------------------------------------------------
// Kernel 3: output projection (unchanged — verified).
// ---------------------------------------------------------------------------
__global__ __launch_bounds__(256) void k_out(
    const unsigned short* __restrict__ a,    // [8192][1024] bf16
    const unsigned short* __restrict__ wq,   // [1024][1024] bf16
    const float* __restrict__ bias,
    float* __restrict__ out)                 // [8192][1024] fp32
{
    __shared__ unsigned short SM[16384];

    const int tid  = threadIdx.x;
    const int wave = tid >> 6, lane = tid & 63;
    const int quad = lane >> 4, l16 = lane & 15;
    const int wm = wave >> 1, wn = wave & 1;

    const int fid  = blockIdx.y * 8 + blockIdx.x;
    const int nfid = (fid & 7) * 64 + (fid >> 3);
    const int n0 = (nfid & 7) * 128;
    const int m0 = (nfid >> 3) * 128;

    const int srow = lane >> 2;
    const int sc8  = (lane & 3) * 8;
    const int row0 = wave * 32 + srow;
    const int row1 = row0 + 16;

    floatx4 acc[4][4];
#pragma unroll
    for (int i = 0; i < 4; i++)
#pragma unroll
        for (int j = 0; j < 4; j++) acc[i][j] = (floatx4){0.f, 0.f, 0.f, 0.f};

#define OUT_STAGE(BUF, K0)                                                        \
    do {                                                                          \
        GLD16(&a[(m0 + row0) * 1024 + (K0) + sc8],                                \
              &SM[(BUF) * 8192 + (wave * 32) * 32]);                              \
        GLD16(&a[(m0 + row1) * 1024 + (K0) + sc8],                                \
              &SM[(BUF) * 8192 + (wave * 32 + 16) * 32]);                         \
        GLD16(&wq[(n0 + row0) * 1024 + (K0) + sc8],                               \
              &SM[(BUF) * 8192 + 4096 + (wave * 32) * 32]);                       \
        GLD16(&wq[(n0 + row1) * 1024 + (K0) + sc8],                               \
              &SM[(BUF) * 8192 + 4096 + (wave * 32 + 16) * 32]);                  \
    } while (0)

    OUT_STAGE(0, 0);
    int buf = 0;
    for (int k0 = 0; k0 < 1024; k0 += 32) {
        __syncthreads();
        if (k0 + 32 < 1024) OUT_STAGE(buf ^ 1, k0 + 32);

        const unsigned short* Ab = &SM[buf * 8192];
        const unsigned short* Bb = &SM[buf * 8192 + 4096];
        short8 af[4], bfv[4];
#pragma unroll
        for (int mi = 0; mi < 4; mi++)
            af[mi] = *(const short8*)&Ab[(wm * 64 + mi * 16 + l16) * 32 + quad * 8];
#pragma unroll
        for (int ni = 0; ni < 4; ni++)
            bfv[ni] = *(const short8*)&Bb[(wn * 64 + ni * 16 + l16) * 32 + quad * 8];
#pragma unroll
        for (int mi = 0; mi < 4; mi++)
#pragma unroll
            for (int ni = 0; ni < 4; ni++)
                acc[mi][ni] = mfma16(af[mi], bfv[ni], acc[mi][ni]);
        buf ^= 1;
    }
#undef OUT_STAGE

#pragma unroll
    for (int ni = 0; ni < 4; ni++) {
        const int col = n0 + wn * 64 + ni * 16 + l16;
        const float bv = bias[col];
#pragma unroll
        for (int mi = 0; mi < 4; mi++) {
            const int mbase = m0 + wm * 64 + mi * 16 + quad * 4;
#pragma unroll
            for (int r = 0; r < 4; r++)
                out[(mbase + r) * 1024 + col] = acc[mi][ni][r] + bv;
        }
    }
}

// ---------------------------------------------------------------------------
extern "C" void kernel_launch(void* const* d_in, const int* in_sizes, int n_in,
                              void* d_out, int out_size, void* d_ws, size_t ws_size,
                              hipStream_t stream) {
    const float* x    = (const float*)d_in[0];
    const float* wqkv = (const float*)d_in[1];
    const float* wout = (const float*)d_in[2];
    const float* bout = (const float*)d_in[3];
    float* out = (float*)d_out;

    unsigned short* ws = (unsigned short*)d_ws;
    unsigned short* xb    = ws;                  // x bf16
    unsigned short* wqkvb = xb + 8388608;
    unsigned short* woutb = wqkvb + 3145728;
    unsigned short* qb    = woutb + 1048576;     // q [bh][t][d]
    unsigned short* kb    = qb + 8388608;        // k [bh][t][d]
    unsigned short* vb    = kb + 8388608;        // v [bh][d][t]
    unsigned short* ob    = vb + 8388608;        // attn out

    k_cvt<<<2048, 256, 0, stream>>>(x,    xb,    8388608 / 4);
    k_cvt<<<1024, 256, 0, stream>>>(wqkv, wqkvb, 3145728 / 4);
    k_cvt<<<512,  256, 0, stream>>>(wout, woutb, 1048576 / 4);

    k_qkv<<<dim3(24, 64), 256, 0, stream>>>(xb, wqkvb, qb, kb, vb);
    k_attn<<<512, 256, 0, stream>>>(qb, kb, vb, (__hip_bfloat16*)ob);
    k_out<<<dim3(8, 64), 256, 0, stream>>>(ob, woutb, bout, out);
}

// Round 6
// 268.357 us; speedup vs baseline: 1.1629x; 1.1629x over previous
//
#include <hip/hip_runtime.h>
#include <hip/hip_bf16.h>

// Problem: B=4, T=2048, DIM=1024, H=16, DH=64.  fp32 in/out, bf16 MFMA inside.
// qkv col o = d*48 + kk*16 + h (d outermost, h innermost).

typedef __attribute__((ext_vector_type(8))) short short8;
typedef __attribute__((ext_vector_type(4))) float floatx4;
typedef __attribute__((ext_vector_type(16))) float floatx16;

static __device__ __forceinline__ floatx4 mfma16(short8 a, short8 b, floatx4 c) {
    return __builtin_amdgcn_mfma_f32_16x16x32_bf16(a, b, c, 0, 0, 0);
}
static __device__ __forceinline__ floatx16 mfma32(short8 a, short8 b, floatx16 c) {
    return __builtin_amdgcn_mfma_f32_32x32x16_bf16(a, b, c, 0, 0, 0);
}

static __device__ __forceinline__ unsigned short f2bf_bits(float f) {
    __hip_bfloat16 h = __float2bfloat16(f);
    return *reinterpret_cast<unsigned short*>(&h);
}

static __device__ __forceinline__ float fast_exp2(float x) {
#if __has_builtin(__builtin_amdgcn_exp2f)
    return __builtin_amdgcn_exp2f(x);
#else
    return exp2f(x);
#endif
}

// pack two f32 -> one u32 of 2 bf16 (lo in [15:0], hi in [31:16])
static __device__ __forceinline__ unsigned cvt_pk_bf16(float lo, float hi) {
    unsigned r;
    asm("v_cvt_pk_bf16_f32 %0, %1, %2" : "=v"(r) : "v"(lo), "v"(hi));
    return r;
}

// m214-verified idiom: swap(pk(p0,p1), pk(p4,p5)) -> both outputs usable.
static __device__ __forceinline__ void plane32_swap(unsigned& x, unsigned& y) {
#if __has_builtin(__builtin_amdgcn_permlane32_swap)
    typedef unsigned int uintx2 __attribute__((ext_vector_type(2)));
    uintx2 r = __builtin_amdgcn_permlane32_swap(x, y, false, false);
    x = r[0];
    y = r[1];
#else
    asm volatile("v_permlane32_swap_b32 %0, %1" : "+v"(x), "+v"(y));
#endif
}

// async global->LDS, 16 B per lane; LDS dest = wave-uniform base + lane*16
#define GLD16(gptr, ldsptr)                                                  \
    __builtin_amdgcn_global_load_lds(                                        \
        (const __attribute__((address_space(1))) void*)(gptr),               \
        (__attribute__((address_space(3))) void*)(ldsptr), 16, 0, 0)

// ---------------------------------------------------------------------------
// Kernel 0: fp32 -> bf16 conversion
// ---------------------------------------------------------------------------
__global__ __launch_bounds__(256) void k_cvt(
    const float* __restrict__ src, unsigned short* __restrict__ dst, int n4)
{
    typedef __attribute__((ext_vector_type(4))) unsigned short ushort4v;
    for (int i = blockIdx.x * blockDim.x + threadIdx.x; i < n4;
         i += gridDim.x * blockDim.x) {
        const float4 v = ((const float4*)src)[i];
        ushort4v o;
        o.x = f2bf_bits(v.x);
        o.y = f2bf_bits(v.y);
        o.z = f2bf_bits(v.z);
        o.w = f2bf_bits(v.w);
        ((ushort4v*)dst)[i] = o;
    }
}

// ---------------------------------------------------------------------------
// Kernel 1: QKV projection.  NEW this round: 3-buffer staging with counted
// s_waitcnt vmcnt(4) + raw s_barrier (T4) — the __syncthreads-implied
// vmcnt(0) drained the in-flight prefetch every K-step (the m97-structure
// ~20% stall).  Stage i+2 issued at iter i; buffer written at i+2 was last
// read at i-1 (two barriers back) -> race-free.  Fragment/epilogue code
// unchanged (verified).
// ---------------------------------------------------------------------------
__global__ __launch_bounds__(256) void k_qkv(
    const unsigned short* __restrict__ x,   // [8192][1024] bf16
    const unsigned short* __restrict__ wq,  // [3072][1024] bf16
    unsigned short* __restrict__ qb,        // [64 bh][2048 t][64 d]
    unsigned short* __restrict__ kb,        // [64 bh][2048 t][64 d]
    unsigned short* __restrict__ vb)        // [64 bh][64 d][2048 t]
{
    // 3 buffers x 8192 shorts ([A|B] each 4096); epilogue reuses [0,9216).
    __shared__ unsigned short SM[24576];

    const int tid  = threadIdx.x;
    const int wave = tid >> 6, lane = tid & 63;
    const int quad = lane >> 4, l16 = lane & 15;
    const int wm = wave >> 1, wn = wave & 1;

    const int fid  = blockIdx.y * 24 + blockIdx.x;
    const int nfid = (fid & 7) * 192 + (fid >> 3);
    const int bx = nfid % 24;
    const int m0 = (nfid / 24) * 128;
    const int kk = bx >> 3;
    const int cb = bx & 7;

    const int srow = lane >> 2;          // 0..15
    const int sc8  = (lane & 3) * 8;     // 0,8,16,24
    const int row0 = wave * 32 + srow;
    const int row1 = row0 + 16;
    int bn0, bn1;
    if (kk < 2) {
        bn0 = (row0 & 63) * 48 + kk * 16 + cb * 2 + (row0 >> 6);
        bn1 = (row1 & 63) * 48 + kk * 16 + cb * 2 + (row1 >> 6);
    } else {
        bn0 = (cb * 8 + (row0 >> 4)) * 48 + 32 + (row0 & 15);
        bn1 = (cb * 8 + (row1 >> 4)) * 48 + 32 + (row1 & 15);
    }

    floatx4 acc[4][4];
#pragma unroll
    for (int i = 0; i < 4; i++)
#pragma unroll
        for (int j = 0; j < 4; j++) acc[i][j] = (floatx4){0.f, 0.f, 0.f, 0.f};

#define QKV_STAGE(BUF, K0)                                                        \
    do {                                                                          \
        GLD16(&x[(m0 + row0) * 1024 + (K0) + sc8],                                \
              &SM[(BUF) * 8192 + (wave * 32) * 32]);                              \
        GLD16(&x[(m0 + row1) * 1024 + (K0) + sc8],                                \
              &SM[(BUF) * 8192 + (wave * 32 + 16) * 32]);                         \
        GLD16(&wq[bn0 * 1024 + (K0) + sc8],                                       \
              &SM[(BUF) * 8192 + 4096 + (wave * 32) * 32]);                       \
        GLD16(&wq[bn1 * 1024 + (K0) + sc8],                                       \
              &SM[(BUF) * 8192 + 4096 + (wave * 32 + 16) * 32]);                  \
    } while (0)

    QKV_STAGE(0, 0);
    QKV_STAGE(1, 32);
    for (int i = 0; i < 32; ++i) {
        // counted wait: stage(i) done, stage(i+1)'s 4 loads stay in flight
        if (i < 31) {
            asm volatile("s_waitcnt vmcnt(4)" ::: "memory");
        } else {
            asm volatile("s_waitcnt vmcnt(0)" ::: "memory");
        }
        __builtin_amdgcn_s_barrier();
        __builtin_amdgcn_sched_barrier(0);
        if (i < 30) QKV_STAGE((i + 2) % 3, (i + 2) * 32);

        const unsigned short* Ab = &SM[(i % 3) * 8192];
        const unsigned short* Bb = Ab + 4096;
        short8 af[4], bfv[4];
#pragma unroll
        for (int mi = 0; mi < 4; mi++)
            af[mi] = *(const short8*)&Ab[(wm * 64 + mi * 16 + l16) * 32 + quad * 8];
#pragma unroll
        for (int ni = 0; ni < 4; ni++)
            bfv[ni] = *(const short8*)&Bb[(wn * 64 + ni * 16 + l16) * 32 + quad * 8];
#pragma unroll
        for (int mi = 0; mi < 4; mi++)
#pragma unroll
            for (int ni = 0; ni < 4; ni++)
                acc[mi][ni] = mfma16(af[mi], bfv[ni], acc[mi][ni]);
    }
    __syncthreads();   // all waves done with SM before epilogue reuse

    if (kk == 2) {
#pragma unroll
        for (int ni = 0; ni < 4; ni++) {
            const int d = cb * 8 + wn * 4 + ni;
#pragma unroll
            for (int mi = 0; mi < 4; mi++) {
                const int m  = m0 + wm * 64 + mi * 16 + quad * 4;
                const int b  = m >> 11;
                const int tt = m & 2047;
                ushort4 pk;
                pk.x = f2bf_bits(acc[mi][ni][0]);
                pk.y = f2bf_bits(acc[mi][ni][1]);
                pk.z = f2bf_bits(acc[mi][ni][2]);
                pk.w = f2bf_bits(acc[mi][ni][3]);
                *(ushort4*)&vb[((b * 16 + l16) * 64 + d) * 2048 + tt] = pk;
            }
        }
    } else {
        const float scale = (kk == 0) ? 0.045084220027780106f : 1.0f;  // log2(e)/32
        unsigned short* dst = (kk == 0) ? qb : kb;
        const int b = m0 >> 11, tt0 = m0 & 2047;
#pragma unroll
        for (int s = 0; s < 2; s++) {
            if (wn == s) {
#pragma unroll
                for (int ni = 0; ni < 4; ni++) {
                    const int d = ni * 16 + l16;
#pragma unroll
                    for (int mi = 0; mi < 4; mi++) {
                        const int tl = wm * 64 + mi * 16 + quad * 4;
#pragma unroll
                        for (int r = 0; r < 4; r++)
                            SM[(tl + r) * 72 + d] = f2bf_bits(acc[mi][ni][r] * scale);
                    }
                }
            }
            __syncthreads();
#pragma unroll
            for (int u = 0; u < 4; u++) {
                const int w  = tid + u * 256;
                const int tl = w >> 3;
                const int ch = (w & 7) * 8;
                *(uint4*)&dst[((b * 16 + cb * 2 + s) * 2048 + tt0 + tl) * 64 + ch] =
                    *(const uint4*)&SM[tl * 72 + ch];
            }
            __syncthreads();
        }
    }
#undef QKV_STAGE
}

// ---------------------------------------------------------------------------
// Kernel 2: flash attention — round-3 structure restored (verified 83.6 µs):
// 32x32x16 swapped QK, in-register softmax via cvt_pk+permlane32, 64-key
// LDS tiles, reg prefetch, 4 waves x 64 qrows.  Only change: raw s_barrier
// instead of __syncthreads at loop end (drops the vmcnt(0) drain of the
// just-issued prefetch; its wait moves into next iter's ds_write dep).
// ---------------------------------------------------------------------------
__global__ __launch_bounds__(256, 2) void k_attn(
    const unsigned short* __restrict__ qt,  // [64][2048][64]  (bh, t, d)
    const unsigned short* __restrict__ kt,  // [64][2048][64]
    const unsigned short* __restrict__ vg,  // [64][64][2048]  (bh, d, t)
    __hip_bfloat16* __restrict__ og)        // [4][2048][1024]
{
    __shared__ unsigned short Ks[64 * 72];  // [key][d]
    __shared__ unsigned short Vt[64 * 72];  // [d][key]

    const int tid  = threadIdx.x;
    const int wave = tid >> 6, lane = tid & 63;
    const int l31  = lane & 31, hi = lane >> 5;
    const int blk = blockIdx.x;
    const int bh  = (blk & 7) | ((blk >> 6) << 3);  // XCD-affine
    const int q0  = ((blk >> 3) & 7) * 256;
    const int qr  = q0 + wave * 64;

    // Q fragments (B operand [16 dk][32 qrow]: col=l31=qrow, k=hi*8+j)
    short8 qf[2][4];
#pragma unroll
    for (int qb2 = 0; qb2 < 2; qb2++)
#pragma unroll
        for (int ks = 0; ks < 4; ks++)
            qf[qb2][ks] = *(const short8*)
                &qt[(bh * 2048 + qr + qb2 * 32 + l31) * 64 + ks * 16 + hi * 8];

    float lsum[2] = {0.f, 0.f};
    floatx16 o[2][2];
#pragma unroll
    for (int qb2 = 0; qb2 < 2; qb2++)
#pragma unroll
        for (int db = 0; db < 2; db++)
#pragma unroll
            for (int r = 0; r < 16; r++) o[qb2][db][r] = 0.f;

    // staging: thread -> K/V row tid>>2 (0..63), shorts (tid&3)*16 (2 x uint4)
    const int sr = tid >> 2, sc = (tid & 3) * 16;

    uint4 rka = *(const uint4*)&kt[(bh * 2048 + sr) * 64 + sc];
    uint4 rkb = *(const uint4*)&kt[(bh * 2048 + sr) * 64 + sc + 8];
    uint4 rva = *(const uint4*)&vg[(bh * 64 + sr) * 2048 + sc];
    uint4 rvb = *(const uint4*)&vg[(bh * 64 + sr) * 2048 + sc + 8];

    for (int j0 = 0; j0 < 2048; j0 += 64) {
        *(uint4*)&Ks[sr * 72 + sc]     = rka;
        *(uint4*)&Ks[sr * 72 + sc + 8] = rkb;
        *(uint4*)&Vt[sr * 72 + sc]     = rva;
        *(uint4*)&Vt[sr * 72 + sc + 8] = rvb;
        asm volatile("s_waitcnt lgkmcnt(0)" ::: "memory");
        __builtin_amdgcn_s_barrier();
        __builtin_amdgcn_sched_barrier(0);
        if (j0 + 64 < 2048) {  // prefetch next tile; consumed at next loop top
            rka = *(const uint4*)&kt[(bh * 2048 + j0 + 64 + sr) * 64 + sc];
            rkb = *(const uint4*)&kt[(bh * 2048 + j0 + 64 + sr) * 64 + sc + 8];
            rva = *(const uint4*)&vg[(bh * 64 + sr) * 2048 + j0 + 64 + sc];
            rvb = *(const uint4*)&vg[(bh * 64 + sr) * 2048 + j0 + 64 + sc + 8];
        }

#pragma unroll
        for (int kb2 = 0; kb2 < 2; kb2++) {   // 32-key blocks
            // K fragments (A operand [32 key][16 dk]: row=l31, k=hi*8+j)
            short8 kf[4];
#pragma unroll
            for (int ks = 0; ks < 4; ks++)
                kf[ks] = *(const short8*)
                    &Ks[(kb2 * 32 + l31) * 72 + ks * 16 + hi * 8];

            // S^T = K Q^T
            floatx16 st[2];
#pragma unroll
            for (int qb2 = 0; qb2 < 2; qb2++)
#pragma unroll
                for (int r = 0; r < 16; r++) st[qb2][r] = 0.f;
            __builtin_amdgcn_s_setprio(1);
#pragma unroll
            for (int ks = 0; ks < 4; ks++)
#pragma unroll
                for (int qb2 = 0; qb2 < 2; qb2++)
                    st[qb2] = mfma32(kf[ks], qf[qb2][ks], st[qb2]);
            __builtin_amdgcn_s_setprio(0);

            // softmax in-register; build PV A-frags via cvt_pk + permlane32
            short8 paf[2][2];
#pragma unroll
            for (int qb2 = 0; qb2 < 2; qb2++) {
                float p[16];
#pragma unroll
                for (int r = 0; r < 16; r++) p[r] = fast_exp2(st[qb2][r]);
                lsum[qb2] += (((p[0] + p[1]) + (p[2] + p[3])) +
                              ((p[4] + p[5]) + (p[6] + p[7]))) +
                             (((p[8] + p[9]) + (p[10] + p[11])) +
                              ((p[12] + p[13]) + (p[14] + p[15])));
#pragma unroll
                for (int hf = 0; hf < 2; hf++) {
                    const int r0 = hf * 8;
                    unsigned c01 = cvt_pk_bf16(p[r0 + 0], p[r0 + 1]);
                    unsigned c23 = cvt_pk_bf16(p[r0 + 2], p[r0 + 3]);
                    unsigned c45 = cvt_pk_bf16(p[r0 + 4], p[r0 + 5]);
                    unsigned c67 = cvt_pk_bf16(p[r0 + 6], p[r0 + 7]);
                    plane32_swap(c01, c45);  // -> a0 (keys hi*8+0,1), a2 (+4,5)
                    plane32_swap(c23, c67);  // -> a1 (keys hi*8+2,3), a3 (+6,7)
                    uint4 t4 = {c01, c23, c45, c67};
                    paf[qb2][hf] = *reinterpret_cast<short8*>(&t4);
                }
            }

            // O += P V   (B operand V [16 key][32 d]: col=l31=d, k=hi*8+j)
            short8 vf[2][2];
#pragma unroll
            for (int db = 0; db < 2; db++)
#pragma unroll
                for (int hf = 0; hf < 2; hf++)
                    vf[db][hf] = *(const short8*)
                        &Vt[(db * 32 + l31) * 72 + kb2 * 32 + hf * 16 + hi * 8];
            __builtin_amdgcn_s_setprio(1);
#pragma unroll
            for (int qb2 = 0; qb2 < 2; qb2++)
#pragma unroll
                for (int db = 0; db < 2; db++)
#pragma unroll
                    for (int hf = 0; hf < 2; hf++)
                        o[qb2][db] = mfma32(paf[qb2][hf], vf[db][hf], o[qb2][db]);
            __builtin_amdgcn_s_setprio(0);
        }
        // raw barrier: no vmcnt drain of the in-flight prefetch
        asm volatile("" ::: "memory");
        __builtin_amdgcn_s_barrier();
        __builtin_amdgcn_sched_barrier(0);
    }

    // each lane summed its hi-half keys; partner lane holds the complement
    lsum[0] += __shfl_xor(lsum[0], 32);
    lsum[1] += __shfl_xor(lsum[1], 32);

    // epilogue: o / l -> [b][t][h*64+d];  D layout: col=l31=d,
    // row(qrow) = (r&3) + 8*(r>>2) + 4*hi
    const int b = bh >> 4, h = bh & 15;
#pragma unroll
    for (int qb2 = 0; qb2 < 2; qb2++) {
#pragma unroll
        for (int r = 0; r < 16; r++) {
            const int qrl = (r & 3) + 8 * (r >> 2) + 4 * hi;
            const float inv = 1.0f / __shfl(lsum[qb2], qrl);
            const int t = qr + qb2 * 32 + qrl;
#pragma unroll
            for (int db = 0; db < 2; db++)
                og[(b * 2048 + t) * 1024 + h * 64 + db * 32 + l31] =
                    __float2bfloat16(o[qb2][db][r] * inv);
        }
    }
}

// ---------------------------------------------------------------------------
// Kernel 3: output projection.  Same counted-vmcnt 3-buffer staging.
// ---------------------------------------------------------------------------
__global__ __launch_bounds__(256) void k_out(
    const unsigned short* __restrict__ a,    // [8192][1024] bf16
    const unsigned short* __restrict__ wq,   // [1024][1024] bf16
    const float* __restrict__ bias,
    float* __restrict__ out)                 // [8192][1024] fp32
{
    __shared__ unsigned short SM[24576];

    const int tid  = threadIdx.x;
    const int wave = tid >> 6, lane = tid & 63;
    const int quad = lane >> 4, l16 = lane & 15;
    const int wm = wave >> 1, wn = wave & 1;

    const int fid  = blockIdx.y * 8 + blockIdx.x;
    const int nfid = (fid & 7) * 64 + (fid >> 3);
    const int n0 = (nfid & 7) * 128;
    const int m0 = (nfid >> 3) * 128;

    const int srow = lane >> 2;
    const int sc8  = (lane & 3) * 8;
    const int row0 = wave * 32 + srow;
    const int row1 = row0 + 16;

    floatx4 acc[4][4];
#pragma unroll
    for (int i = 0; i < 4; i++)
#pragma unroll
        for (int j = 0; j < 4; j++) acc[i][j] = (floatx4){0.f, 0.f, 0.f, 0.f};

#define OUT_STAGE(BUF, K0)                                                        \
    do {                                                                          \
        GLD16(&a[(m0 + row0) * 1024 + (K0) + sc8],                                \
              &SM[(BUF) * 8192 + (wave * 32) * 32]);                              \
        GLD16(&a[(m0 + row1) * 1024 + (K0) + sc8],                                \
              &SM[(BUF) * 8192 + (wave * 32 + 16) * 32]);                         \
        GLD16(&wq[(n0 + row0) * 1024 + (K0) + sc8],                               \
              &SM[(BUF) * 8192 + 4096 + (wave * 32) * 32]);                       \
        GLD16(&wq[(n0 + row1) * 1024 + (K0) + sc8],                               \
              &SM[(BUF) * 8192 + 4096 + (wave * 32 + 16) * 32]);                  \
    } while (0)

    OUT_STAGE(0, 0);
    OUT_STAGE(1, 32);
    for (int i = 0; i < 32; ++i) {
        if (i < 31) {
            asm volatile("s_waitcnt vmcnt(4)" ::: "memory");
        } else {
            asm volatile("s_waitcnt vmcnt(0)" ::: "memory");
        }
        __builtin_amdgcn_s_barrier();
        __builtin_amdgcn_sched_barrier(0);
        if (i < 30) OUT_STAGE((i + 2) % 3, (i + 2) * 32);

        const unsigned short* Ab = &SM[(i % 3) * 8192];
        const unsigned short* Bb = Ab + 4096;
        short8 af[4], bfv[4];
#pragma unroll
        for (int mi = 0; mi < 4; mi++)
            af[mi] = *(const short8*)&Ab[(wm * 64 + mi * 16 + l16) * 32 + quad * 8];
#pragma unroll
        for (int ni = 0; ni < 4; ni++)
            bfv[ni] = *(const short8*)&Bb[(wn * 64 + ni * 16 + l16) * 32 + quad * 8];
#pragma unroll
        for (int mi = 0; mi < 4; mi++)
#pragma unroll
            for (int ni = 0; ni < 4; ni++)
                acc[mi][ni] = mfma16(af[mi], bfv[ni], acc[mi][ni]);
    }
#undef OUT_STAGE

#pragma unroll
    for (int ni = 0; ni < 4; ni++) {
        const int col = n0 + wn * 64 + ni * 16 + l16;
        const float bv = bias[col];
#pragma unroll
        for (int mi = 0; mi < 4; mi++) {
            const int mbase = m0 + wm * 64 + mi * 16 + quad * 4;
#pragma unroll
            for (int r = 0; r < 4; r++)
                out[(mbase + r) * 1024 + col] = acc[mi][ni][r] + bv;
        }
    }
}

// ---------------------------------------------------------------------------
extern "C" void kernel_launch(void* const* d_in, const int* in_sizes, int n_in,
                              void* d_out, int out_size, void* d_ws, size_t ws_size,
                              hipStream_t stream) {
    const float* x    = (const float*)d_in[0];
    const float* wqkv = (const float*)d_in[1];
    const float* wout = (const float*)d_in[2];
    const float* bout = (const float*)d_in[3];
    float* out = (float*)d_out;

    unsigned short* ws = (unsigned short*)d_ws;
    unsigned short* xb    = ws;                  // x bf16
    unsigned short* wqkvb = xb + 8388608;
    unsigned short* woutb = wqkvb + 3145728;
    unsigned short* qb    = woutb + 1048576;     // q [bh][t][d]
    unsigned short* kb    = qb + 8388608;        // k [bh][t][d]
    unsigned short* vb    = kb + 8388608;        // v [bh][d][t]
    unsigned short* ob    = vb + 8388608;        // attn out

    k_cvt<<<2048, 256, 0, stream>>>(x,    xb,    8388608 / 4);
    k_cvt<<<1024, 256, 0, stream>>>(wqkv, wqkvb, 3145728 / 4);
    k_cvt<<<512,  256, 0, stream>>>(wout, woutb, 1048576 / 4);

    k_qkv<<<dim3(24, 64), 256, 0, stream>>>(xb, wqkvb, qb, kb, vb);
    k_attn<<<512, 256, 0, stream>>>(qb, kb, vb, (__hip_bfloat16*)ob);
    k_out<<<dim3(8, 64), 256, 0, stream>>>(ob, woutb, bout, out);
}

// Round 7
// 258.033 us; speedup vs baseline: 1.2095x; 1.0400x over previous
//
#include <hip/hip_runtime.h>
#include <hip/hip_bf16.h>

// Problem: B=4, T=2048, DIM=1024, H=16, DH=64.  fp32 in/out, bf16 MFMA inside.
// qkv col o = d*48 + kk*16 + h (d outermost, h innermost).

typedef __attribute__((ext_vector_type(8))) short short8;
typedef __attribute__((ext_vector_type(4))) float floatx4;
typedef __attribute__((ext_vector_type(16))) float floatx16;

static __device__ __forceinline__ floatx4 mfma16(short8 a, short8 b, floatx4 c) {
    return __builtin_amdgcn_mfma_f32_16x16x32_bf16(a, b, c, 0, 0, 0);
}
static __device__ __forceinline__ floatx16 mfma32(short8 a, short8 b, floatx16 c) {
    return __builtin_amdgcn_mfma_f32_32x32x16_bf16(a, b, c, 0, 0, 0);
}

static __device__ __forceinline__ unsigned short f2bf_bits(float f) {
    __hip_bfloat16 h = __float2bfloat16(f);
    return *reinterpret_cast<unsigned short*>(&h);
}

static __device__ __forceinline__ float fast_exp2(float x) {
#if __has_builtin(__builtin_amdgcn_exp2f)
    return __builtin_amdgcn_exp2f(x);
#else
    return exp2f(x);
#endif
}

// pack two f32 -> one u32 of 2 bf16 (lo in [15:0], hi in [31:16])
static __device__ __forceinline__ unsigned cvt_pk_bf16(float lo, float hi) {
    unsigned r;
    asm("v_cvt_pk_bf16_f32 %0, %1, %2" : "=v"(r) : "v"(lo), "v"(hi));
    return r;
}

// m214-verified idiom: swap(pk(p0,p1), pk(p4,p5)) -> both outputs usable.
static __device__ __forceinline__ void plane32_swap(unsigned& x, unsigned& y) {
#if __has_builtin(__builtin_amdgcn_permlane32_swap)
    typedef unsigned int uintx2 __attribute__((ext_vector_type(2)));
    uintx2 r = __builtin_amdgcn_permlane32_swap(x, y, false, false);
    x = r[0];
    y = r[1];
#else
    asm volatile("v_permlane32_swap_b32 %0, %1" : "+v"(x), "+v"(y));
#endif
}

// async global->LDS, 16 B per lane; LDS dest = wave-uniform base + lane*16
#define GLD16(gptr, ldsptr)                                                  \
    __builtin_amdgcn_global_load_lds(                                        \
        (const __attribute__((address_space(1))) void*)(gptr),               \
        (__attribute__((address_space(3))) void*)(ldsptr), 16, 0, 0)

// ---------------------------------------------------------------------------
// Kernel 0: fp32 -> bf16 conversion, all three tensors in one launch.
// Region boundaries are multiples of 64 -> wave-uniform branches.
// ---------------------------------------------------------------------------
__global__ __launch_bounds__(256) void k_cvt3(
    const float* __restrict__ s0,   // x     [8388608 floats]
    const float* __restrict__ s1,   // wqkv  [3145728 floats]
    const float* __restrict__ s2,   // wout  [1048576 floats]
    unsigned short* __restrict__ dst)  // ws: xb @0, wqkvb @8388608, woutb @11534336
{
    typedef __attribute__((ext_vector_type(4))) unsigned short ushort4v;
    for (int i = blockIdx.x * blockDim.x + threadIdx.x; i < 3145728;
         i += gridDim.x * blockDim.x) {
        const float4* sp;
        unsigned short* dp;
        int li;
        if (i < 2097152)      { sp = (const float4*)s0; dp = dst;            li = i; }
        else if (i < 2883584) { sp = (const float4*)s1; dp = dst + 8388608;  li = i - 2097152; }
        else                  { sp = (const float4*)s2; dp = dst + 11534336; li = i - 2883584; }
        const float4 v = sp[li];
        ushort4v o;
        o.x = f2bf_bits(v.x);
        o.y = f2bf_bits(v.y);
        o.z = f2bf_bits(v.z);
        o.w = f2bf_bits(v.w);
        ((ushort4v*)dp)[li] = o;
    }
}

// ---------------------------------------------------------------------------
// Kernel 1: QKV projection — round-2 verified version (2-phase dbuf with
// __syncthreads, XCD-chunked swizzle).  r6's counted-vmcnt 3-buf regressed
// ~13 µs -> reverted.
// ---------------------------------------------------------------------------
__global__ __launch_bounds__(256) void k_qkv(
    const unsigned short* __restrict__ x,   // [8192][1024] bf16
    const unsigned short* __restrict__ wq,  // [3072][1024] bf16
    unsigned short* __restrict__ qb,        // [64 bh][2048 t][64 d]
    unsigned short* __restrict__ kb,        // [64 bh][2048 t][64 d]
    unsigned short* __restrict__ vb)        // [64 bh][64 d][2048 t]
{
    __shared__ unsigned short SM[16384];

    const int tid  = threadIdx.x;
    const int wave = tid >> 6, lane = tid & 63;
    const int quad = lane >> 4, l16 = lane & 15;
    const int wm = wave >> 1, wn = wave & 1;

    const int fid  = blockIdx.y * 24 + blockIdx.x;
    const int nfid = (fid & 7) * 192 + (fid >> 3);
    const int bx = nfid % 24;
    const int m0 = (nfid / 24) * 128;
    const int kk = bx >> 3;
    const int cb = bx & 7;

    const int srow = lane >> 2;          // 0..15
    const int sc8  = (lane & 3) * 8;     // 0,8,16,24
    const int row0 = wave * 32 + srow;
    const int row1 = row0 + 16;
    int bn0, bn1;
    if (kk < 2) {
        bn0 = (row0 & 63) * 48 + kk * 16 + cb * 2 + (row0 >> 6);
        bn1 = (row1 & 63) * 48 + kk * 16 + cb * 2 + (row1 >> 6);
    } else {
        bn0 = (cb * 8 + (row0 >> 4)) * 48 + 32 + (row0 & 15);
        bn1 = (cb * 8 + (row1 >> 4)) * 48 + 32 + (row1 & 15);
    }

    floatx4 acc[4][4];
#pragma unroll
    for (int i = 0; i < 4; i++)
#pragma unroll
        for (int j = 0; j < 4; j++) acc[i][j] = (floatx4){0.f, 0.f, 0.f, 0.f};

#define QKV_STAGE(BUF, K0)                                                        \
    do {                                                                          \
        GLD16(&x[(m0 + row0) * 1024 + (K0) + sc8],                                \
              &SM[(BUF) * 8192 + (wave * 32) * 32]);                              \
        GLD16(&x[(m0 + row1) * 1024 + (K0) + sc8],                                \
              &SM[(BUF) * 8192 + (wave * 32 + 16) * 32]);                         \
        GLD16(&wq[bn0 * 1024 + (K0) + sc8],                                       \
              &SM[(BUF) * 8192 + 4096 + (wave * 32) * 32]);                       \
        GLD16(&wq[bn1 * 1024 + (K0) + sc8],                                       \
              &SM[(BUF) * 8192 + 4096 + (wave * 32 + 16) * 32]);                  \
    } while (0)

    QKV_STAGE(0, 0);
    int buf = 0;
    for (int k0 = 0; k0 < 1024; k0 += 32) {
        __syncthreads();
        if (k0 + 32 < 1024) QKV_STAGE(buf ^ 1, k0 + 32);

        const unsigned short* Ab = &SM[buf * 8192];
        const unsigned short* Bb = Ab + 4096;
        short8 af[4], bfv[4];
#pragma unroll
        for (int mi = 0; mi < 4; mi++)
            af[mi] = *(const short8*)&Ab[(wm * 64 + mi * 16 + l16) * 32 + quad * 8];
#pragma unroll
        for (int ni = 0; ni < 4; ni++)
            bfv[ni] = *(const short8*)&Bb[(wn * 64 + ni * 16 + l16) * 32 + quad * 8];
#pragma unroll
        for (int mi = 0; mi < 4; mi++)
#pragma unroll
            for (int ni = 0; ni < 4; ni++)
                acc[mi][ni] = mfma16(af[mi], bfv[ni], acc[mi][ni]);
        buf ^= 1;
    }
    __syncthreads();

    if (kk == 2) {
#pragma unroll
        for (int ni = 0; ni < 4; ni++) {
            const int d = cb * 8 + wn * 4 + ni;
#pragma unroll
            for (int mi = 0; mi < 4; mi++) {
                const int m  = m0 + wm * 64 + mi * 16 + quad * 4;
                const int b  = m >> 11;
                const int tt = m & 2047;
                ushort4 pk;
                pk.x = f2bf_bits(acc[mi][ni][0]);
                pk.y = f2bf_bits(acc[mi][ni][1]);
                pk.z = f2bf_bits(acc[mi][ni][2]);
                pk.w = f2bf_bits(acc[mi][ni][3]);
                *(ushort4*)&vb[((b * 16 + l16) * 64 + d) * 2048 + tt] = pk;
            }
        }
    } else {
        const float scale = (kk == 0) ? 0.045084220027780106f : 1.0f;  // log2(e)/32
        unsigned short* dst = (kk == 0) ? qb : kb;
        const int b = m0 >> 11, tt0 = m0 & 2047;
#pragma unroll
        for (int s = 0; s < 2; s++) {
            if (wn == s) {
#pragma unroll
                for (int ni = 0; ni < 4; ni++) {
                    const int d = ni * 16 + l16;
#pragma unroll
                    for (int mi = 0; mi < 4; mi++) {
                        const int tl = wm * 64 + mi * 16 + quad * 4;
#pragma unroll
                        for (int r = 0; r < 4; r++)
                            SM[(tl + r) * 72 + d] = f2bf_bits(acc[mi][ni][r] * scale);
                    }
                }
            }
            __syncthreads();
#pragma unroll
            for (int u = 0; u < 4; u++) {
                const int w  = tid + u * 256;
                const int tl = w >> 3;
                const int ch = (w & 7) * 8;
                *(uint4*)&dst[((b * 16 + cb * 2 + s) * 2048 + tt0 + tl) * 64 + ch] =
                    *(const uint4*)&SM[tl * 72 + ch];
            }
            __syncthreads();
        }
    }
#undef QKV_STAGE
}

// ---------------------------------------------------------------------------
// Kernel 2: flash attention.  NEW this round: K/V LDS DOUBLE-BUFFER -> one
// barrier per 64-key tile (was 2) and the serial per-tile head
// {vmcnt->ds_write->lgkmcnt(0)->barrier} becomes: writes for tile j+1 issue
// at top of iter j and drain UNDER the compute phase; lgkmcnt(0) lands after
// compute (~free).  Single reg-set suffices (store precedes reload in body).
// Compute code identical to the verified r3 structure (32x32x16 swapped QK,
// in-register softmax via cvt_pk+permlane32, 4 waves x 64 qrows).
// ---------------------------------------------------------------------------
__global__ __launch_bounds__(256, 2) void k_attn(
    const unsigned short* __restrict__ qt,  // [64][2048][64]  (bh, t, d)
    const unsigned short* __restrict__ kt,  // [64][2048][64]
    const unsigned short* __restrict__ vg,  // [64][64][2048]  (bh, d, t)
    __hip_bfloat16* __restrict__ og)        // [4][2048][1024]
{
    __shared__ unsigned short Ks[2 * 64 * 72];  // [buf][key][d]
    __shared__ unsigned short Vt[2 * 64 * 72];  // [buf][d][key]

    const int tid  = threadIdx.x;
    const int wave = tid >> 6, lane = tid & 63;
    const int l31  = lane & 31, hi = lane >> 5;
    const int blk = blockIdx.x;
    const int bh  = (blk & 7) | ((blk >> 6) << 3);  // XCD-affine
    const int q0  = ((blk >> 3) & 7) * 256;
    const int qr  = q0 + wave * 64;

    // Q fragments (B operand [16 dk][32 qrow]: col=l31=qrow, k=hi*8+j)
    short8 qf[2][4];
#pragma unroll
    for (int qb2 = 0; qb2 < 2; qb2++)
#pragma unroll
        for (int ks = 0; ks < 4; ks++)
            qf[qb2][ks] = *(const short8*)
                &qt[(bh * 2048 + qr + qb2 * 32 + l31) * 64 + ks * 16 + hi * 8];

    float lsum[2] = {0.f, 0.f};
    floatx16 o[2][2];
#pragma unroll
    for (int qb2 = 0; qb2 < 2; qb2++)
#pragma unroll
        for (int db = 0; db < 2; db++)
#pragma unroll
            for (int r = 0; r < 16; r++) o[qb2][db][r] = 0.f;

    // staging: thread -> K/V row tid>>2 (0..63), shorts (tid&3)*16 (2 x uint4)
    const int sr = tid >> 2, sc = (tid & 3) * 16;

    // prologue: tile 0 -> buf 0; tile 1 regs in flight
    uint4 rka = *(const uint4*)&kt[(bh * 2048 + sr) * 64 + sc];
    uint4 rkb = *(const uint4*)&kt[(bh * 2048 + sr) * 64 + sc + 8];
    uint4 rva = *(const uint4*)&vg[(bh * 64 + sr) * 2048 + sc];
    uint4 rvb = *(const uint4*)&vg[(bh * 64 + sr) * 2048 + sc + 8];
    *(uint4*)&Ks[sr * 72 + sc]     = rka;
    *(uint4*)&Ks[sr * 72 + sc + 8] = rkb;
    *(uint4*)&Vt[sr * 72 + sc]     = rva;
    *(uint4*)&Vt[sr * 72 + sc + 8] = rvb;
    rka = *(const uint4*)&kt[(bh * 2048 + 64 + sr) * 64 + sc];
    rkb = *(const uint4*)&kt[(bh * 2048 + 64 + sr) * 64 + sc + 8];
    rva = *(const uint4*)&vg[(bh * 64 + sr) * 2048 + 64 + sc];
    rvb = *(const uint4*)&vg[(bh * 64 + sr) * 2048 + 64 + sc + 8];
    asm volatile("s_waitcnt lgkmcnt(0)" ::: "memory");
    __builtin_amdgcn_sched_barrier(0);

    int c = 0;
    for (int j0 = 0; j0 < 2048; j0 += 64) {
        __builtin_amdgcn_s_barrier();        // buf[c] ready; buf[c^1] free
        __builtin_amdgcn_sched_barrier(0);
        const int nx = c ^ 1;
        if (j0 + 64 < 2048) {                // write tile j+1 into buf[c^1]
            *(uint4*)&Ks[nx * 4608 + sr * 72 + sc]     = rka;
            *(uint4*)&Ks[nx * 4608 + sr * 72 + sc + 8] = rkb;
            *(uint4*)&Vt[nx * 4608 + sr * 72 + sc]     = rva;
            *(uint4*)&Vt[nx * 4608 + sr * 72 + sc + 8] = rvb;
        }
        if (j0 + 128 < 2048) {               // issue loads for tile j+2
            rka = *(const uint4*)&kt[(bh * 2048 + j0 + 128 + sr) * 64 + sc];
            rkb = *(const uint4*)&kt[(bh * 2048 + j0 + 128 + sr) * 64 + sc + 8];
            rva = *(const uint4*)&vg[(bh * 64 + sr) * 2048 + j0 + 128 + sc];
            rvb = *(const uint4*)&vg[(bh * 64 + sr) * 2048 + j0 + 128 + sc + 8];
        }
        const unsigned short* Kc = &Ks[c * 4608];
        const unsigned short* Vc = &Vt[c * 4608];

#pragma unroll
        for (int kb2 = 0; kb2 < 2; kb2++) {   // 32-key blocks
            // K fragments (A operand [32 key][16 dk]: row=l31, k=hi*8+j)
            short8 kf[4];
#pragma unroll
            for (int ks = 0; ks < 4; ks++)
                kf[ks] = *(const short8*)
                    &Kc[(kb2 * 32 + l31) * 72 + ks * 16 + hi * 8];

            // S^T = K Q^T
            floatx16 st[2];
#pragma unroll
            for (int qb2 = 0; qb2 < 2; qb2++)
#pragma unroll
                for (int r = 0; r < 16; r++) st[qb2][r] = 0.f;
            __builtin_amdgcn_s_setprio(1);
#pragma unroll
            for (int ks = 0; ks < 4; ks++)
#pragma unroll
                for (int qb2 = 0; qb2 < 2; qb2++)
                    st[qb2] = mfma32(kf[ks], qf[qb2][ks], st[qb2]);
            __builtin_amdgcn_s_setprio(0);

            // softmax in-register; build PV A-frags via cvt_pk + permlane32
            short8 paf[2][2];
#pragma unroll
            for (int qb2 = 0; qb2 < 2; qb2++) {
                float p[16];
#pragma unroll
                for (int r = 0; r < 16; r++) p[r] = fast_exp2(st[qb2][r]);
                lsum[qb2] += (((p[0] + p[1]) + (p[2] + p[3])) +
                              ((p[4] + p[5]) + (p[6] + p[7]))) +
                             (((p[8] + p[9]) + (p[10] + p[11])) +
                              ((p[12] + p[13]) + (p[14] + p[15])));
#pragma unroll
                for (int hf = 0; hf < 2; hf++) {
                    const int r0 = hf * 8;
                    unsigned c01 = cvt_pk_bf16(p[r0 + 0], p[r0 + 1]);
                    unsigned c23 = cvt_pk_bf16(p[r0 + 2], p[r0 + 3]);
                    unsigned c45 = cvt_pk_bf16(p[r0 + 4], p[r0 + 5]);
                    unsigned c67 = cvt_pk_bf16(p[r0 + 6], p[r0 + 7]);
                    plane32_swap(c01, c45);  // -> a0 (keys hi*8+0,1), a2 (+4,5)
                    plane32_swap(c23, c67);  // -> a1 (keys hi*8+2,3), a3 (+6,7)
                    uint4 t4 = {c01, c23, c45, c67};
                    paf[qb2][hf] = *reinterpret_cast<short8*>(&t4);
                }
            }

            // O += P V   (B operand V [16 key][32 d]: col=l31=d, k=hi*8+j)
            short8 vf[2][2];
#pragma unroll
            for (int db = 0; db < 2; db++)
#pragma unroll
                for (int hf = 0; hf < 2; hf++)
                    vf[db][hf] = *(const short8*)
                        &Vc[(db * 32 + l31) * 72 + kb2 * 32 + hf * 16 + hi * 8];
            __builtin_amdgcn_s_setprio(1);
#pragma unroll
            for (int qb2 = 0; qb2 < 2; qb2++)
#pragma unroll
                for (int db = 0; db < 2; db++)
#pragma unroll
                    for (int hf = 0; hf < 2; hf++)
                        o[qb2][db] = mfma32(paf[qb2][hf], vf[db][hf], o[qb2][db]);
            __builtin_amdgcn_s_setprio(0);
        }
        // my ds_writes (issued pre-compute) + ds_reads drained before barrier
        asm volatile("s_waitcnt lgkmcnt(0)" ::: "memory");
        __builtin_amdgcn_sched_barrier(0);
        c ^= 1;
    }

    // each lane summed its hi-half keys; partner lane holds the complement
    lsum[0] += __shfl_xor(lsum[0], 32);
    lsum[1] += __shfl_xor(lsum[1], 32);

    // epilogue: o / l -> [b][t][h*64+d];  D layout: col=l31=d,
    // row(qrow) = (r&3) + 8*(r>>2) + 4*hi
    const int b = bh >> 4, h = bh & 15;
#pragma unroll
    for (int qb2 = 0; qb2 < 2; qb2++) {
#pragma unroll
        for (int r = 0; r < 16; r++) {
            const int qrl = (r & 3) + 8 * (r >> 2) + 4 * hi;
            const float inv = 1.0f / __shfl(lsum[qb2], qrl);
            const int t = qr + qb2 * 32 + qrl;
#pragma unroll
            for (int db = 0; db < 2; db++)
                og[(b * 2048 + t) * 1024 + h * 64 + db * 32 + l31] =
                    __float2bfloat16(o[qb2][db][r] * inv);
        }
    }
}

// ---------------------------------------------------------------------------
// Kernel 3: output projection — round-2 verified version (2-phase dbuf).
// ---------------------------------------------------------------------------
__global__ __launch_bounds__(256) void k_out(
    const unsigned short* __restrict__ a,    // [8192][1024] bf16
    const unsigned short* __restrict__ wq,   // [1024][1024] bf16
    const float* __restrict__ bias,
    float* __restrict__ out)                 // [8192][1024] fp32
{
    __shared__ unsigned short SM[16384];

    const int tid  = threadIdx.x;
    const int wave = tid >> 6, lane = tid & 63;
    const int quad = lane >> 4, l16 = lane & 15;
    const int wm = wave >> 1, wn = wave & 1;

    const int fid  = blockIdx.y * 8 + blockIdx.x;
    const int nfid = (fid & 7) * 64 + (fid >> 3);
    const int n0 = (nfid & 7) * 128;
    const int m0 = (nfid >> 3) * 128;

    const int srow = lane >> 2;
    const int sc8  = (lane & 3) * 8;
    const int row0 = wave * 32 + srow;
    const int row1 = row0 + 16;

    floatx4 acc[4][4];
#pragma unroll
    for (int i = 0; i < 4; i++)
#pragma unroll
        for (int j = 0; j < 4; j++) acc[i][j] = (floatx4){0.f, 0.f, 0.f, 0.f};

#define OUT_STAGE(BUF, K0)                                                        \
    do {                                                                          \
        GLD16(&a[(m0 + row0) * 1024 + (K0) + sc8],                                \
              &SM[(BUF) * 8192 + (wave * 32) * 32]);                              \
        GLD16(&a[(m0 + row1) * 1024 + (K0) + sc8],                                \
              &SM[(BUF) * 8192 + (wave * 32 + 16) * 32]);                         \
        GLD16(&wq[(n0 + row0) * 1024 + (K0) + sc8],                               \
              &SM[(BUF) * 8192 + 4096 + (wave * 32) * 32]);                       \
        GLD16(&wq[(n0 + row1) * 1024 + (K0) + sc8],                               \
              &SM[(BUF) * 8192 + 4096 + (wave * 32 + 16) * 32]);                  \
    } while (0)

    OUT_STAGE(0, 0);
    int buf = 0;
    for (int k0 = 0; k0 < 1024; k0 += 32) {
        __syncthreads();
        if (k0 + 32 < 1024) OUT_STAGE(buf ^ 1, k0 + 32);

        const unsigned short* Ab = &SM[buf * 8192];
        const unsigned short* Bb = Ab + 4096;
        short8 af[4], bfv[4];
#pragma unroll
        for (int mi = 0; mi < 4; mi++)
            af[mi] = *(const short8*)&Ab[(wm * 64 + mi * 16 + l16) * 32 + quad * 8];
#pragma unroll
        for (int ni = 0; ni < 4; ni++)
            bfv[ni] = *(const short8*)&Bb[(wn * 64 + ni * 16 + l16) * 32 + quad * 8];
#pragma unroll
        for (int mi = 0; mi < 4; mi++)
#pragma unroll
            for (int ni = 0; ni < 4; ni++)
                acc[mi][ni] = mfma16(af[mi], bfv[ni], acc[mi][ni]);
        buf ^= 1;
    }
#undef OUT_STAGE

#pragma unroll
    for (int ni = 0; ni < 4; ni++) {
        const int col = n0 + wn * 64 + ni * 16 + l16;
        const float bv = bias[col];
#pragma unroll
        for (int mi = 0; mi < 4; mi++) {
            const int mbase = m0 + wm * 64 + mi * 16 + quad * 4;
#pragma unroll
            for (int r = 0; r < 4; r++)
                out[(mbase + r) * 1024 + col] = acc[mi][ni][r] + bv;
        }
    }
}

// ---------------------------------------------------------------------------
extern "C" void kernel_launch(void* const* d_in, const int* in_sizes, int n_in,
                              void* d_out, int out_size, void* d_ws, size_t ws_size,
                              hipStream_t stream) {
    const float* x    = (const float*)d_in[0];
    const float* wqkv = (const float*)d_in[1];
    const float* wout = (const float*)d_in[2];
    const float* bout = (const float*)d_in[3];
    float* out = (float*)d_out;

    unsigned short* ws = (unsigned short*)d_ws;
    unsigned short* xb    = ws;                  // x bf16
    unsigned short* wqkvb = xb + 8388608;
    unsigned short* woutb = wqkvb + 3145728;
    unsigned short* qb    = woutb + 1048576;     // q [bh][t][d]
    unsigned short* kb    = qb + 8388608;        // k [bh][t][d]
    unsigned short* vb    = kb + 8388608;        // v [bh][d][t]
    unsigned short* ob    = vb + 8388608;        // attn out

    k_cvt3<<<2048, 256, 0, stream>>>(x, wqkv, wout, ws);

    k_qkv<<<dim3(24, 64), 256, 0, stream>>>(xb, wqkvb, qb, kb, vb);
    k_attn<<<512, 256, 0, stream>>>(qb, kb, vb, (__hip_bfloat16*)ob);
    k_out<<<dim3(8, 64), 256, 0, stream>>>(ob, woutb, bout, out);
}

// Round 8
// 254.011 us; speedup vs baseline: 1.2286x; 1.0158x over previous
//
#include <hip/hip_runtime.h>
#include <hip/hip_bf16.h>

// Problem: B=4, T=2048, DIM=1024, H=16, DH=64.  fp32 in/out, bf16 MFMA inside.
// qkv col o = d*48 + kk*16 + h (d outermost, h innermost).

typedef __attribute__((ext_vector_type(8))) short short8;
typedef __attribute__((ext_vector_type(4))) float floatx4;
typedef __attribute__((ext_vector_type(16))) float floatx16;

static __device__ __forceinline__ floatx4 mfma16(short8 a, short8 b, floatx4 c) {
    return __builtin_amdgcn_mfma_f32_16x16x32_bf16(a, b, c, 0, 0, 0);
}
static __device__ __forceinline__ floatx16 mfma32(short8 a, short8 b, floatx16 c) {
    return __builtin_amdgcn_mfma_f32_32x32x16_bf16(a, b, c, 0, 0, 0);
}

static __device__ __forceinline__ unsigned short f2bf_bits(float f) {
    __hip_bfloat16 h = __float2bfloat16(f);
    return *reinterpret_cast<unsigned short*>(&h);
}

static __device__ __forceinline__ float fast_exp2(float x) {
#if __has_builtin(__builtin_amdgcn_exp2f)
    return __builtin_amdgcn_exp2f(x);
#else
    return exp2f(x);
#endif
}

// pack two f32 -> one u32 of 2 bf16 (lo in [15:0], hi in [31:16])
static __device__ __forceinline__ unsigned cvt_pk_bf16(float lo, float hi) {
    unsigned r;
    asm("v_cvt_pk_bf16_f32 %0, %1, %2" : "=v"(r) : "v"(lo), "v"(hi));
    return r;
}

// m214-verified idiom: swap(pk(p0,p1), pk(p4,p5)) -> both outputs usable.
static __device__ __forceinline__ void plane32_swap(unsigned& x, unsigned& y) {
#if __has_builtin(__builtin_amdgcn_permlane32_swap)
    typedef unsigned int uintx2 __attribute__((ext_vector_type(2)));
    uintx2 r = __builtin_amdgcn_permlane32_swap(x, y, false, false);
    x = r[0];
    y = r[1];
#else
    asm volatile("v_permlane32_swap_b32 %0, %1" : "+v"(x), "+v"(y));
#endif
}

// async global->LDS, 16 B per lane; LDS dest = wave-uniform base + lane*16
#define GLD16(gptr, ldsptr)                                                  \
    __builtin_amdgcn_global_load_lds(                                        \
        (const __attribute__((address_space(1))) void*)(gptr),               \
        (__attribute__((address_space(3))) void*)(ldsptr), 16, 0, 0)

// ---------------------------------------------------------------------------
// Kernel 0: fp32 -> bf16 conversion (three separate launches — r3 verified;
// the r7 merged variant was neutral-to-negative).
// ---------------------------------------------------------------------------
__global__ __launch_bounds__(256) void k_cvt(
    const float* __restrict__ src, unsigned short* __restrict__ dst, int n4)
{
    typedef __attribute__((ext_vector_type(4))) unsigned short ushort4v;
    for (int i = blockIdx.x * blockDim.x + threadIdx.x; i < n4;
         i += gridDim.x * blockDim.x) {
        const float4 v = ((const float4*)src)[i];
        ushort4v o;
        o.x = f2bf_bits(v.x);
        o.y = f2bf_bits(v.y);
        o.z = f2bf_bits(v.z);
        o.w = f2bf_bits(v.w);
        ((ushort4v*)dst)[i] = o;
    }
}

// ---------------------------------------------------------------------------
// Kernel 1: QKV projection — round-2 verified version (2-phase dbuf with
// __syncthreads, XCD-chunked swizzle).
// ---------------------------------------------------------------------------
__global__ __launch_bounds__(256) void k_qkv(
    const unsigned short* __restrict__ x,   // [8192][1024] bf16
    const unsigned short* __restrict__ wq,  // [3072][1024] bf16
    unsigned short* __restrict__ qb,        // [64 bh][2048 t][64 d]
    unsigned short* __restrict__ kb,        // [64 bh][2048 t][64 d]
    unsigned short* __restrict__ vb)        // [64 bh][64 d][2048 t]
{
    __shared__ unsigned short SM[16384];

    const int tid  = threadIdx.x;
    const int wave = tid >> 6, lane = tid & 63;
    const int quad = lane >> 4, l16 = lane & 15;
    const int wm = wave >> 1, wn = wave & 1;

    const int fid  = blockIdx.y * 24 + blockIdx.x;
    const int nfid = (fid & 7) * 192 + (fid >> 3);
    const int bx = nfid % 24;
    const int m0 = (nfid / 24) * 128;
    const int kk = bx >> 3;
    const int cb = bx & 7;

    const int srow = lane >> 2;          // 0..15
    const int sc8  = (lane & 3) * 8;     // 0,8,16,24
    const int row0 = wave * 32 + srow;
    const int row1 = row0 + 16;
    int bn0, bn1;
    if (kk < 2) {
        bn0 = (row0 & 63) * 48 + kk * 16 + cb * 2 + (row0 >> 6);
        bn1 = (row1 & 63) * 48 + kk * 16 + cb * 2 + (row1 >> 6);
    } else {
        bn0 = (cb * 8 + (row0 >> 4)) * 48 + 32 + (row0 & 15);
        bn1 = (cb * 8 + (row1 >> 4)) * 48 + 32 + (row1 & 15);
    }

    floatx4 acc[4][4];
#pragma unroll
    for (int i = 0; i < 4; i++)
#pragma unroll
        for (int j = 0; j < 4; j++) acc[i][j] = (floatx4){0.f, 0.f, 0.f, 0.f};

#define QKV_STAGE(BUF, K0)                                                        \
    do {                                                                          \
        GLD16(&x[(m0 + row0) * 1024 + (K0) + sc8],                                \
              &SM[(BUF) * 8192 + (wave * 32) * 32]);                              \
        GLD16(&x[(m0 + row1) * 1024 + (K0) + sc8],                                \
              &SM[(BUF) * 8192 + (wave * 32 + 16) * 32]);                         \
        GLD16(&wq[bn0 * 1024 + (K0) + sc8],                                       \
              &SM[(BUF) * 8192 + 4096 + (wave * 32) * 32]);                       \
        GLD16(&wq[bn1 * 1024 + (K0) + sc8],                                       \
              &SM[(BUF) * 8192 + 4096 + (wave * 32 + 16) * 32]);                  \
    } while (0)

    QKV_STAGE(0, 0);
    int buf = 0;
    for (int k0 = 0; k0 < 1024; k0 += 32) {
        __syncthreads();
        if (k0 + 32 < 1024) QKV_STAGE(buf ^ 1, k0 + 32);

        const unsigned short* Ab = &SM[buf * 8192];
        const unsigned short* Bb = Ab + 4096;
        short8 af[4], bfv[4];
#pragma unroll
        for (int mi = 0; mi < 4; mi++)
            af[mi] = *(const short8*)&Ab[(wm * 64 + mi * 16 + l16) * 32 + quad * 8];
#pragma unroll
        for (int ni = 0; ni < 4; ni++)
            bfv[ni] = *(const short8*)&Bb[(wn * 64 + ni * 16 + l16) * 32 + quad * 8];
#pragma unroll
        for (int mi = 0; mi < 4; mi++)
#pragma unroll
            for (int ni = 0; ni < 4; ni++)
                acc[mi][ni] = mfma16(af[mi], bfv[ni], acc[mi][ni]);
        buf ^= 1;
    }
    __syncthreads();

    if (kk == 2) {
#pragma unroll
        for (int ni = 0; ni < 4; ni++) {
            const int d = cb * 8 + wn * 4 + ni;
#pragma unroll
            for (int mi = 0; mi < 4; mi++) {
                const int m  = m0 + wm * 64 + mi * 16 + quad * 4;
                const int b  = m >> 11;
                const int tt = m & 2047;
                ushort4 pk;
                pk.x = f2bf_bits(acc[mi][ni][0]);
                pk.y = f2bf_bits(acc[mi][ni][1]);
                pk.z = f2bf_bits(acc[mi][ni][2]);
                pk.w = f2bf_bits(acc[mi][ni][3]);
                *(ushort4*)&vb[((b * 16 + l16) * 64 + d) * 2048 + tt] = pk;
            }
        }
    } else {
        const float scale = (kk == 0) ? 0.045084220027780106f : 1.0f;  // log2(e)/32
        unsigned short* dst = (kk == 0) ? qb : kb;
        const int b = m0 >> 11, tt0 = m0 & 2047;
#pragma unroll
        for (int s = 0; s < 2; s++) {
            if (wn == s) {
#pragma unroll
                for (int ni = 0; ni < 4; ni++) {
                    const int d = ni * 16 + l16;
#pragma unroll
                    for (int mi = 0; mi < 4; mi++) {
                        const int tl = wm * 64 + mi * 16 + quad * 4;
#pragma unroll
                        for (int r = 0; r < 4; r++)
                            SM[(tl + r) * 72 + d] = f2bf_bits(acc[mi][ni][r] * scale);
                    }
                }
            }
            __syncthreads();
#pragma unroll
            for (int u = 0; u < 4; u++) {
                const int w  = tid + u * 256;
                const int tl = w >> 3;
                const int ch = (w & 7) * 8;
                *(uint4*)&dst[((b * 16 + cb * 2 + s) * 2048 + tt0 + tl) * 64 + ch] =
                    *(const uint4*)&SM[tl * 72 + ch];
            }
            __syncthreads();
        }
    }
#undef QKV_STAGE
}

// ---------------------------------------------------------------------------
// Kernel 2: flash attention.  NEW this round: CROSS-TILE SOFTWARE PIPELINE.
// Diagnosis: MFMA(66k)+VALU(78k)+LDS(61k) cycles/CU sum to the measured 200k
// — the pipes run serially because all waves are barrier-phase-locked.  Fix:
// carry stP (scores of the next 32-key unit) across iterations so each iter
// executes {QK(next unit) MFMA ∥ softmax(current) VALU} -> PV, giving the
// scheduler both pipe types in every window.  4-buffer LDS rotation (73.7 KB,
// 2 blk/CU) makes tile j+1's K readable during iter j; writes go to buf
// (j+2)&3, two barriers ahead of any reader.  Ping-pong is inherent in the
// dataflow (stP consumed in slot A, recomputed in slot B) — no copies, all
// names static (rule #20).  Math identical to the verified r3 kernel.
// ---------------------------------------------------------------------------
__global__ __launch_bounds__(256, 2) void k_attn(
    const unsigned short* __restrict__ qt,  // [64][2048][64]  (bh, t, d)
    const unsigned short* __restrict__ kt,  // [64][2048][64]
    const unsigned short* __restrict__ vg,  // [64][64][2048]  (bh, d, t)
    __hip_bfloat16* __restrict__ og)        // [4][2048][1024]
{
    __shared__ unsigned short Ks[4 * 4608];  // [buf][key][d]   36864 B
    __shared__ unsigned short Vt[4 * 4608];  // [buf][d][key]   36864 B

    const int tid  = threadIdx.x;
    const int wave = tid >> 6, lane = tid & 63;
    const int l31  = lane & 31, hi = lane >> 5;
    const int blk = blockIdx.x;
    const int bh  = (blk & 7) | ((blk >> 6) << 3);  // XCD-affine
    const int q0  = ((blk >> 3) & 7) * 256;
    const int qr  = q0 + wave * 64;

    // Q fragments (B operand [16 dk][32 qrow]: col=l31=qrow, k=hi*8+j)
    short8 qf[2][4];
#pragma unroll
    for (int qb2 = 0; qb2 < 2; qb2++)
#pragma unroll
        for (int ks = 0; ks < 4; ks++)
            qf[qb2][ks] = *(const short8*)
                &qt[(bh * 2048 + qr + qb2 * 32 + l31) * 64 + ks * 16 + hi * 8];

    float lsum[2] = {0.f, 0.f};
    floatx16 o[2][2];
#pragma unroll
    for (int qb2 = 0; qb2 < 2; qb2++)
#pragma unroll
        for (int db = 0; db < 2; db++)
#pragma unroll
            for (int r = 0; r < 16; r++) o[qb2][db][r] = 0.f;

    // staging: thread -> K/V row tid>>2 (0..63), shorts (tid&3)*16
    const int sr = tid >> 2, sc = (tid & 3) * 16;
    const unsigned short* kR = &kt[(bh * 2048 + sr) * 64 + sc];  // tile t: +t*4096
    const unsigned short* vR = &vg[(bh * 64 + sr) * 2048 + sc];  // tile t: +t*64

    uint4 rka, rkb, rva, rvb;
#define LOADT(T)                                                   \
    do {                                                           \
        rka = *(const uint4*)&kR[(T) * 4096];                      \
        rkb = *(const uint4*)&kR[(T) * 4096 + 8];                  \
        rva = *(const uint4*)&vR[(T) * 64];                        \
        rvb = *(const uint4*)&vR[(T) * 64 + 8];                    \
    } while (0)
#define WRITET(B)                                                  \
    do {                                                           \
        *(uint4*)&Ks[(B) * 4608 + sr * 72 + sc]     = rka;         \
        *(uint4*)&Ks[(B) * 4608 + sr * 72 + sc + 8] = rkb;         \
        *(uint4*)&Vt[(B) * 4608 + sr * 72 + sc]     = rva;         \
        *(uint4*)&Vt[(B) * 4608 + sr * 72 + sc + 8] = rvb;         \
    } while (0)

// softmax of a floatx16 pair -> paf frags (verified r3 recipe)
#define SOFTMAX(ST, PAF)                                                        \
    do {                                                                        \
        _Pragma("unroll")                                                       \
        for (int qb2 = 0; qb2 < 2; qb2++) {                                     \
            float p[16];                                                        \
            _Pragma("unroll")                                                   \
            for (int r = 0; r < 16; r++) p[r] = fast_exp2((ST)[qb2][r]);        \
            lsum[qb2] += (((p[0] + p[1]) + (p[2] + p[3])) +                     \
                          ((p[4] + p[5]) + (p[6] + p[7]))) +                    \
                         (((p[8] + p[9]) + (p[10] + p[11])) +                   \
                          ((p[12] + p[13]) + (p[14] + p[15])));                 \
            _Pragma("unroll")                                                   \
            for (int hf = 0; hf < 2; hf++) {                                    \
                const int r0 = hf * 8;                                          \
                unsigned c01 = cvt_pk_bf16(p[r0 + 0], p[r0 + 1]);               \
                unsigned c23 = cvt_pk_bf16(p[r0 + 2], p[r0 + 3]);               \
                unsigned c45 = cvt_pk_bf16(p[r0 + 4], p[r0 + 5]);               \
                unsigned c67 = cvt_pk_bf16(p[r0 + 6], p[r0 + 7]);               \
                plane32_swap(c01, c45);                                         \
                plane32_swap(c23, c67);                                         \
                uint4 t4 = {c01, c23, c45, c67};                                \
                (PAF)[qb2][hf] = *reinterpret_cast<short8*>(&t4);               \
            }                                                                   \
        }                                                                       \
    } while (0)

// PV accumulate: o += paf x V(buf BO, kb2 KB2)
#define PV(PAF, BO, KB2)                                                        \
    do {                                                                        \
        short8 vf[2][2];                                                        \
        _Pragma("unroll")                                                       \
        for (int db = 0; db < 2; db++)                                          \
            _Pragma("unroll")                                                   \
            for (int hf = 0; hf < 2; hf++)                                      \
                vf[db][hf] = *(const short8*)&Vt[(BO) + (db * 32 + l31) * 72 +  \
                                                 (KB2) * 32 + hf * 16 + hi * 8];\
        __builtin_amdgcn_s_setprio(1);                                          \
        _Pragma("unroll")                                                       \
        for (int qb2 = 0; qb2 < 2; qb2++)                                       \
            _Pragma("unroll")                                                   \
            for (int db = 0; db < 2; db++)                                      \
                _Pragma("unroll")                                               \
                for (int hf = 0; hf < 2; hf++)                                  \
                    o[qb2][db] = mfma32((PAF)[qb2][hf], vf[db][hf], o[qb2][db]);\
        __builtin_amdgcn_s_setprio(0);                                          \
    } while (0)

// QK: ST = K(buf BO, kb2 KB2) x Q^T  (8 mfma)
#define QK(ST, BO, KB2)                                                         \
    do {                                                                        \
        short8 kf[4];                                                           \
        _Pragma("unroll")                                                       \
        for (int ks = 0; ks < 4; ks++)                                          \
            kf[ks] = *(const short8*)&Ks[(BO) + ((KB2) * 32 + l31) * 72 +       \
                                         ks * 16 + hi * 8];                     \
        _Pragma("unroll")                                                       \
        for (int qb2 = 0; qb2 < 2; qb2++)                                       \
            _Pragma("unroll")                                                   \
            for (int r = 0; r < 16; r++) (ST)[qb2][r] = 0.f;                    \
        __builtin_amdgcn_s_setprio(1);                                          \
        _Pragma("unroll")                                                       \
        for (int ks = 0; ks < 4; ks++)                                          \
            _Pragma("unroll")                                                   \
            for (int qb2 = 0; qb2 < 2; qb2++)                                   \
                (ST)[qb2] = mfma32(kf[ks], qf[qb2][ks], (ST)[qb2]);             \
        __builtin_amdgcn_s_setprio(0);                                          \
    } while (0)

    // prologue: tiles 0,1 in LDS; tile 2 in regs; stP = QK(tile0, kb2=0)
    LOADT(0);
    WRITET(0);
    LOADT(1);
    WRITET(1);
    LOADT(2);
    asm volatile("s_waitcnt lgkmcnt(0)" ::: "memory");
    __builtin_amdgcn_s_barrier();
    __builtin_amdgcn_sched_barrier(0);

    floatx16 stP[2];
    QK(stP, 0, 0);

    for (int j = 0; j < 32; ++j) {
        const int bj  = (j & 3) * 4608;
        const int bj1 = ((j + 1) & 3) * 4608;
        if (j <= 29) WRITET((j + 2) & 3);   // tile j+2 (regs from iter j-1)
        if (j <= 28) LOADT(j + 3);          // issue loads for tile j+3

        // slot A: QK(tile j, kb2=1) -> stN  ∥  softmax(stP = tile j, kb2=0)
        floatx16 stN[2];
        QK(stN, bj, 1);
        short8 pafP[2][2];
        SOFTMAX(stP, pafP);
        PV(pafP, bj, 0);

        // slot B: QK(tile j+1, kb2=0) -> stP  ∥  softmax(stN = tile j, kb2=1)
        if (j <= 30) QK(stP, bj1, 0);
        short8 pafN[2][2];
        SOFTMAX(stN, pafN);
        PV(pafN, bj, 1);

        asm volatile("s_waitcnt lgkmcnt(0)" ::: "memory");
        __builtin_amdgcn_s_barrier();
        __builtin_amdgcn_sched_barrier(0);
    }
#undef QK
#undef PV
#undef SOFTMAX
#undef WRITET
#undef LOADT

    // each lane summed its hi-half keys; partner lane holds the complement
    lsum[0] += __shfl_xor(lsum[0], 32);
    lsum[1] += __shfl_xor(lsum[1], 32);

    // epilogue: o / l -> [b][t][h*64+d];  D layout: col=l31=d,
    // row(qrow) = (r&3) + 8*(r>>2) + 4*hi
    const int b = bh >> 4, h = bh & 15;
#pragma unroll
    for (int qb2 = 0; qb2 < 2; qb2++) {
#pragma unroll
        for (int r = 0; r < 16; r++) {
            const int qrl = (r & 3) + 8 * (r >> 2) + 4 * hi;
            const float inv = 1.0f / __shfl(lsum[qb2], qrl);
            const int t = qr + qb2 * 32 + qrl;
#pragma unroll
            for (int db = 0; db < 2; db++)
                og[(b * 2048 + t) * 1024 + h * 64 + db * 32 + l31] =
                    __float2bfloat16(o[qb2][db][r] * inv);
        }
    }
}

// ---------------------------------------------------------------------------
// Kernel 3: output projection — round-2 verified version (2-phase dbuf).
// ---------------------------------------------------------------------------
__global__ __launch_bounds__(256) void k_out(
    const unsigned short* __restrict__ a,    // [8192][1024] bf16
    const unsigned short* __restrict__ wq,   // [1024][1024] bf16
    const float* __restrict__ bias,
    float* __restrict__ out)                 // [8192][1024] fp32
{
    __shared__ unsigned short SM[16384];

    const int tid  = threadIdx.x;
    const int wave = tid >> 6, lane = tid & 63;
    const int quad = lane >> 4, l16 = lane & 15;
    const int wm = wave >> 1, wn = wave & 1;

    const int fid  = blockIdx.y * 8 + blockIdx.x;
    const int nfid = (fid & 7) * 64 + (fid >> 3);
    const int n0 = (nfid & 7) * 128;
    const int m0 = (nfid >> 3) * 128;

    const int srow = lane >> 2;
    const int sc8  = (lane & 3) * 8;
    const int row0 = wave * 32 + srow;
    const int row1 = row0 + 16;

    floatx4 acc[4][4];
#pragma unroll
    for (int i = 0; i < 4; i++)
#pragma unroll
        for (int j = 0; j < 4; j++) acc[i][j] = (floatx4){0.f, 0.f, 0.f, 0.f};

#define OUT_STAGE(BUF, K0)                                                        \
    do {                                                                          \
        GLD16(&a[(m0 + row0) * 1024 + (K0) + sc8],                                \
              &SM[(BUF) * 8192 + (wave * 32) * 32]);                              \
        GLD16(&a[(m0 + row1) * 1024 + (K0) + sc8],                                \
              &SM[(BUF) * 8192 + (wave * 32 + 16) * 32]);                         \
        GLD16(&wq[(n0 + row0) * 1024 + (K0) + sc8],                               \
              &SM[(BUF) * 8192 + 4096 + (wave * 32) * 32]);                       \
        GLD16(&wq[(n0 + row1) * 1024 + (K0) + sc8],                               \
              &SM[(BUF) * 8192 + 4096 + (wave * 32 + 16) * 32]);                  \
    } while (0)

    OUT_STAGE(0, 0);
    int buf = 0;
    for (int k0 = 0; k0 < 1024; k0 += 32) {
        __syncthreads();
        if (k0 + 32 < 1024) OUT_STAGE(buf ^ 1, k0 + 32);

        const unsigned short* Ab = &SM[buf * 8192];
        const unsigned short* Bb = Ab + 4096;
        short8 af[4], bfv[4];
#pragma unroll
        for (int mi = 0; mi < 4; mi++)
            af[mi] = *(const short8*)&Ab[(wm * 64 + mi * 16 + l16) * 32 + quad * 8];
#pragma unroll
        for (int ni = 0; ni < 4; ni++)
            bfv[ni] = *(const short8*)&Bb[(wn * 64 + ni * 16 + l16) * 32 + quad * 8];
#pragma unroll
        for (int mi = 0; mi < 4; mi++)
#pragma unroll
            for (int ni = 0; ni < 4; ni++)
                acc[mi][ni] = mfma16(af[mi], bfv[ni], acc[mi][ni]);
        buf ^= 1;
    }
#undef OUT_STAGE

#pragma unroll
    for (int ni = 0; ni < 4; ni++) {
        const int col = n0 + wn * 64 + ni * 16 + l16;
        const float bv = bias[col];
#pragma unroll
        for (int mi = 0; mi < 4; mi++) {
            const int mbase = m0 + wm * 64 + mi * 16 + quad * 4;
#pragma unroll
            for (int r = 0; r < 4; r++)
                out[(mbase + r) * 1024 + col] = acc[mi][ni][r] + bv;
        }
    }
}

// ---------------------------------------------------------------------------
extern "C" void kernel_launch(void* const* d_in, const int* in_sizes, int n_in,
                              void* d_out, int out_size, void* d_ws, size_t ws_size,
                              hipStream_t stream) {
    const float* x    = (const float*)d_in[0];
    const float* wqkv = (const float*)d_in[1];
    const float* wout = (const float*)d_in[2];
    const float* bout = (const float*)d_in[3];
    float* out = (float*)d_out;

    unsigned short* ws = (unsigned short*)d_ws;
    unsigned short* xb    = ws;                  // x bf16
    unsigned short* wqkvb = xb + 8388608;
    unsigned short* woutb = wqkvb + 3145728;
    unsigned short* qb    = woutb + 1048576;     // q [bh][t][d]
    unsigned short* kb    = qb + 8388608;        // k [bh][t][d]
    unsigned short* vb    = kb + 8388608;        // v [bh][d][t]
    unsigned short* ob    = vb + 8388608;        // attn out

    k_cvt<<<2048, 256, 0, stream>>>(x,    xb,    8388608 / 4);
    k_cvt<<<1024, 256, 0, stream>>>(wqkv, wqkvb, 3145728 / 4);
    k_cvt<<<512,  256, 0, stream>>>(wout, woutb, 1048576 / 4);

    k_qkv<<<dim3(24, 64), 256, 0, stream>>>(xb, wqkvb, qb, kb, vb);
    k_attn<<<512, 256, 0, stream>>>(qb, kb, vb, (__hip_bfloat16*)ob);
    k_out<<<dim3(8, 64), 256, 0, stream>>>(ob, woutb, bout, out);
}